// Round 5
// baseline (1005.211 us; speedup 1.0000x reference)
//
#include <hip/hip_runtime.h>
#include <hip/hip_bf16.h>
#include <stdint.h>

#define MAXDEG 64

// ============ SIMPLE PIPELINE, f32 in / f32 OUT (contract-fix round) ============
// All intermediates f32 in reference-natural [T][N][C] layout. One thread per
// output element. Optimize only after this passes and we have counters.

// ---- degree + ELL adjacency (incoming edges per dst) ----
__global__ void k_build_ell(const int* __restrict__ ei, const float* __restrict__ ew,
                            float* __restrict__ deg, unsigned* __restrict__ cnt,
                            int2* __restrict__ ell, int E)
{
    int e = blockIdx.x * 256 + threadIdx.x;
    if (e >= E) return;
    int s = ei[e], d = ei[E + e];
    float w = ew[e];
    atomicAdd(&deg[d], w);
    unsigned slot = atomicAdd(&cnt[d], 1u);
    if (slot < MAXDEG) ell[(size_t)d * MAXDEG + slot] = make_int2(s, __float_as_int(w));
}

// ---- dis = rsqrt(deg + 1) ----
__global__ void k_dis(const float* __restrict__ deg, float* __restrict__ dis, int N)
{
    int i = blockIdx.x * 256 + threadIdx.x;
    if (i < N) dis[i] = rsqrtf(deg[i] + 1.0f);
}

// ---- temporal conv (K=3, zero pad 1) + InstanceNorm over T + ReLU ----
// in : [T][N][CIN] f32, w: [64][CIN][3], out: [T][N][64] f32
template<int CIN>
__global__ void k_conv(const float* __restrict__ xin, const float* __restrict__ cw,
                       const float* __restrict__ cb, const float* __restrict__ gm,
                       const float* __restrict__ bt, float* __restrict__ hout, int N)
{
    int tid = blockIdx.x * 256 + threadIdx.x;
    if (tid >= N * 64) return;
    const int n = tid >> 6, c = tid & 63;

    float acc[12];
    const float bias = cb[c];
    #pragma unroll
    for (int t = 0; t < 12; ++t) acc[t] = bias;

    const float* w = cw + (size_t)c * CIN * 3;
    for (int ci = 0; ci < CIN; ++ci) {
        const float w0 = w[ci * 3 + 0], w1 = w[ci * 3 + 1], w2 = w[ci * 3 + 2];
        float xv[12];
        #pragma unroll
        for (int t = 0; t < 12; ++t) xv[t] = xin[((size_t)t * N + n) * CIN + ci];
        #pragma unroll
        for (int t = 0; t < 12; ++t) {
            float s = xv[t] * w1;
            if (t > 0)  s = fmaf(xv[t - 1], w0, s);
            if (t < 11) s = fmaf(xv[t + 1], w2, s);
            acc[t] += s;
        }
    }
    // InstanceNorm over T (biased var) + affine + ReLU
    float mu = 0.f;
    #pragma unroll
    for (int t = 0; t < 12; ++t) mu += acc[t];
    mu *= (1.f / 12.f);
    float var = 0.f;
    #pragma unroll
    for (int t = 0; t < 12; ++t) { float d = acc[t] - mu; var = fmaf(d, d, var); }
    var *= (1.f / 12.f);
    const float sc = rsqrtf(var + 1e-5f) * gm[c];
    const float sb = bt[c];
    #pragma unroll
    for (int t = 0; t < 12; ++t) {
        float h = fmaf(acc[t] - mu, sc, sb);
        hout[((size_t)t * N + n) * 64 + c] = h > 0.f ? h : 0.f;
    }
}

// ---- xw[t][n][d] = sum_c h[t][n][c] * gw[c][d] ----
__global__ void k_xw(const float* __restrict__ h, const float* __restrict__ gw,
                     float* __restrict__ xw, int total)
{
    int tid = blockIdx.x * 256 + threadIdx.x;
    if (tid >= total) return;
    const int d = tid & 63;
    const size_t base = (size_t)(tid >> 6) * 64;   // (t*N + n)*64
    const float* hr = h + base;
    float a = 0.f;
    for (int c = 0; c < 64; ++c) a = fmaf(hr[c], gw[c * 64 + d], a);
    xw[base + d] = a;
}

// ---- agg[t][n][c] = dis[n]^2*xw[t][n][c] + gb[c] + sum_{e:dst=n} dis[src]*w*dis[n]*xw[t][src][c]
__global__ void k_agg(const float* __restrict__ xw, const int2* __restrict__ ell,
                      const unsigned* __restrict__ cnt, const float* __restrict__ dis,
                      const float* __restrict__ gb, float* __restrict__ agg,
                      int N, int total)
{
    int tid = blockIdx.x * 256 + threadIdx.x;
    if (tid >= total) return;
    const int c = tid & 63;
    const int tn = tid >> 6;          // t*N + n
    const int n = tn % N;
    const size_t base = (size_t)tn * 64;
    const size_t tbase = (size_t)(tn - n) * 64;    // t*N*64
    const float dn = dis[n];
    float a = fmaf(dn * dn, xw[base + c], gb[c]);
    unsigned dg = cnt[n];
    if (dg > MAXDEG) dg = MAXDEG;
    const int2* row = ell + (size_t)n * MAXDEG;
    for (unsigned e = 0; e < dg; ++e) {
        int2 p = row[e];
        unsigned sx = (unsigned)p.x;
        if (sx >= (unsigned)N) continue;           // defensive
        float nrm = dis[sx] * __int_as_float(p.y) * dn;
        a = fmaf(nrm, xw[tbase + (size_t)sx * 64 + c], a);
    }
    agg[base + c] = a;
}

// ---- out[n][o] = ob[o] + (1/12) * sum_t sum_c h2[t][n][c] * ow[c][o] ----
__global__ void k_out(const float* __restrict__ h2, const float* __restrict__ ow,
                      const float* __restrict__ ob, float* __restrict__ dout, int N)
{
    int tid = blockIdx.x * 256 + threadIdx.x;
    if (tid >= N * 32) return;
    const int o = tid & 31, n = tid >> 5;
    float accum = 0.f;
    for (int t = 0; t < 12; ++t) {
        const float* hr = h2 + ((size_t)t * N + n) * 64;
        for (int c = 0; c < 64; ++c) accum = fmaf(hr[c], ow[c * 32 + o], accum);
    }
    float a = ob[o] + accum * (1.f / 12.f);
    dout[(size_t)n * 32 + o] = a;                  // f32 output per reference dtype
}

extern "C" void kernel_launch(void* const* d_in, const int* in_sizes, int n_in,
                              void* d_out, int out_size, void* d_ws, size_t ws_size,
                              hipStream_t stream)
{
    const float* x   = (const float*)d_in[0];
    const int*   ei  = (const int*)d_in[1];
    const float* ew  = (const float*)d_in[2];
    const float* cw1 = (const float*)d_in[3];
    const float* cb1 = (const float*)d_in[4];
    const float* gm1 = (const float*)d_in[5];
    const float* bt1 = (const float*)d_in[6];
    const float* gw1 = (const float*)d_in[7];
    const float* gb1 = (const float*)d_in[8];
    const float* cw2 = (const float*)d_in[9];
    const float* cb2 = (const float*)d_in[10];
    const float* gm2 = (const float*)d_in[11];
    const float* bt2 = (const float*)d_in[12];
    const float* gw2 = (const float*)d_in[13];
    const float* gb2 = (const float*)d_in[14];
    const float* ow  = (const float*)d_in[15];
    const float* ob  = (const float*)d_in[16];

    const int N = in_sizes[0] / (12 * 32);
    const int E = in_sizes[2];
    const int TN64 = 12 * N * 64;

    // workspace layout
    char* p0 = (char*)d_ws;
    char* p = p0;
    float* deg = (float*)p;          p += (size_t)N * 4;
    unsigned* cnt = (unsigned*)p;    p += (size_t)N * 4;   // adjacent to deg: one memset
    float* dis = (float*)p;          p += (size_t)N * 4;
    p = (char*)(((uintptr_t)p + 255) & ~(uintptr_t)255);
    int2* ell = (int2*)p;            p += (size_t)N * MAXDEG * 8;
    p = (char*)(((uintptr_t)p + 255) & ~(uintptr_t)255);
    float* A = (float*)p;            p += (size_t)TN64 * 4;   // conv output h
    float* B = (float*)p;            p += (size_t)TN64 * 4;   // xw
    float* C = (float*)p;            p += (size_t)TN64 * 4;   // agg / next conv input

    const size_t need = (size_t)(p - p0);
    if (ws_size < need) {
        // sentinel: all-zero output -> absmax prints exactly max|ref| (~1.882812e+00)
        hipMemsetAsync(d_out, 0, (size_t)out_size * 4, stream);
        return;
    }

    hipMemsetAsync(deg, 0, (size_t)N * 8, stream);

    const int eb  = (E + 255) / 256;
    const int nb  = (N * 64 + 255) / 256;
    const int tb  = (TN64 + 255) / 256;
    const int ob_ = (N * 32 + 255) / 256;

    k_build_ell<<<eb, 256, 0, stream>>>(ei, ew, deg, cnt, ell, E);
    k_dis<<<(N + 255) / 256, 256, 0, stream>>>(deg, dis, N);

    // layer 1
    k_conv<32><<<nb, 256, 0, stream>>>(x, cw1, cb1, gm1, bt1, A, N);
    k_xw   <<<tb, 256, 0, stream>>>(A, gw1, B, TN64);
    k_agg  <<<tb, 256, 0, stream>>>(B, ell, cnt, dis, gb1, C, N, TN64);
    // layer 2
    k_conv<64><<<nb, 256, 0, stream>>>(C, cw2, cb2, gm2, bt2, A, N);
    k_xw   <<<tb, 256, 0, stream>>>(A, gw2, B, TN64);
    k_agg  <<<tb, 256, 0, stream>>>(B, ell, cnt, dis, gb2, C, N, TN64);
    // output head
    k_out  <<<ob_, 256, 0, stream>>>(C, ow, ob, (float*)d_out, N);
}

// Round 6
// 445.665 us; speedup vs baseline: 2.2555x; 2.2555x over previous
//
#include <hip/hip_runtime.h>
#include <hip/hip_bf16.h>
#include <stdint.h>

#define MAXDEG 64

// ---------------- setup: degree + ELL adjacency (incoming edges per dst) ----------------
__global__ void k_build_ell(const int* __restrict__ ei, const float* __restrict__ ew,
                            float* __restrict__ deg, unsigned* __restrict__ cnt,
                            int2* __restrict__ ell, int E)
{
    int e = blockIdx.x * 256 + threadIdx.x;
    if (e >= E) return;
    int s = ei[e], d = ei[E + e];
    float w = ew[e];
    atomicAdd(&deg[d], w);
    unsigned slot = atomicAdd(&cnt[d], 1u);
    if (slot < MAXDEG) ell[(size_t)d * MAXDEG + slot] = make_int2(s, __float_as_int(w));
}

__global__ void k_dis(const float* __restrict__ deg, float* __restrict__ dis, int N)
{
    int i = blockIdx.x * 256 + threadIdx.x;
    if (i < N) dis[i] = rsqrtf(deg[i] + 1.0f);
}

// ---------------- layer A: conv1d(K=3,pad1) + InstanceNorm(T) + ReLU + (h @ gw) --------
// One wave per node (lane = out channel), 4 nodes per block. All f32.
// FIRST input: [T][N][CIN]; else [N][T*CIN] node-contiguous. Output: [N][T*64].
template<int CIN, bool FIRST>
__global__ __launch_bounds__(256) void k_layer_a(
    const float* __restrict__ x_in,
    const float* __restrict__ cw,     // [64][CIN][3]
    const float* __restrict__ cb, const float* __restrict__ gm, const float* __restrict__ bt,
    const float* __restrict__ gw,     // [64][64] (read from global, L2-broadcast)
    float* __restrict__ xw_out, int N)
{
    constexpr int WROWS = CIN * 3;
    constexpr int WSTR  = WROWS + 1;             // 97 / 193: %32==1 -> conflict-free rows
    constexpr int TILE  = (14 * CIN > 768) ? 14 * CIN : 768;
    __shared__ float lw[64 * WSTR];              // [c][ci*3+k], row stride WSTR
    __shared__ __align__(16) float tile[4][TILE];

    const int tid = threadIdx.x;
    const int nn = tid >> 6;
    const int c = tid & 63;
    int n = blockIdx.x * 4 + nn;
    if (n >= N) n = N - 1;

    // cooperative weight staging (straight copy + row pad)
    for (int g = tid; g < 64 * WROWS; g += 256) {
        int row = g / WROWS, col = g - row * WROWS;
        lw[row * WSTR + col] = cw[g];
    }

    // stage x into tile rows t=-1..12 (rows 0..13), row stride CIN (wave-private slice)
    if (FIRST) {
        #pragma unroll
        for (int it = 0; it < (12 * CIN) / 64; ++it) {
            int i = it * 64 + c;
            int t = i / CIN, ci = i - t * CIN;
            tile[nn][(t + 1) * CIN + ci] = x_in[((size_t)t * N + n) * CIN + ci];
        }
    } else {
        const float* src = x_in + (size_t)n * 768;
        #pragma unroll
        for (int j = 0; j < 3; ++j)
            *(float4*)&tile[nn][CIN + j * 256 + c * 4] = *(const float4*)(src + j * 256 + c * 4);
    }
    if (c < CIN) { tile[nn][c] = 0.f; tile[nn][13 * CIN + c] = 0.f; }
    __syncthreads();   // weights staged by all threads

    // conv: acc[t] = bias + sum_ci sum_k x[t+k-1][ci] * w[c][ci][k]
    float acc[12];
    {
        const float bias = cb[c];
        #pragma unroll
        for (int t = 0; t < 12; ++t) acc[t] = bias;
        const float* xt = tile[nn];
        const float* wrow = lw + c * WSTR;
        #pragma unroll
        for (int cq = 0; cq < CIN / 4; ++cq) {
            float wv[12];
            #pragma unroll
            for (int r = 0; r < 12; ++r) wv[r] = wrow[cq * 12 + r];
            float4 r0 = *(const float4*)(xt + cq * 4);
            float4 r1 = *(const float4*)(xt + CIN + cq * 4);
            #pragma unroll
            for (int t = 0; t < 12; ++t) {
                float4 r2 = *(const float4*)(xt + (t + 2) * CIN + cq * 4);
                acc[t] = fmaf(r0.x, wv[0], acc[t]);
                acc[t] = fmaf(r1.x, wv[1], acc[t]);
                acc[t] = fmaf(r2.x, wv[2], acc[t]);
                acc[t] = fmaf(r0.y, wv[3], acc[t]);
                acc[t] = fmaf(r1.y, wv[4], acc[t]);
                acc[t] = fmaf(r2.y, wv[5], acc[t]);
                acc[t] = fmaf(r0.z, wv[6], acc[t]);
                acc[t] = fmaf(r1.z, wv[7], acc[t]);
                acc[t] = fmaf(r2.z, wv[8], acc[t]);
                acc[t] = fmaf(r0.w, wv[9], acc[t]);
                acc[t] = fmaf(r1.w, wv[10], acc[t]);
                acc[t] = fmaf(r2.w, wv[11], acc[t]);
                r0 = r1; r1 = r2;
            }
        }
    }
    // InstanceNorm over T (biased var) + affine + ReLU  (register-only per (n,c))
    float mu = 0.f;
    #pragma unroll
    for (int t = 0; t < 12; ++t) mu += acc[t];
    mu *= (1.f / 12.f);
    float var = 0.f;
    #pragma unroll
    for (int t = 0; t < 12; ++t) { float d = acc[t] - mu; var = fmaf(d, d, var); }
    var *= (1.f / 12.f);
    const float sc = rsqrtf(var + 1e-5f) * gm[c];
    const float sb = bt[c];
    // reuse wave-private tile slice as h[t][64] (no cross-wave access -> no barrier)
    #pragma unroll
    for (int t = 0; t < 12; ++t) {
        float h = fmaf(acc[t] - mu, sc, sb);
        tile[nn][t * 64 + c] = h > 0.f ? h : 0.f;
    }

    // xw[t][d] = sum_cc h[t][cc] * gw[cc][d]; d = lane; gw rows from global (coalesced)
    float xw[12];
    #pragma unroll
    for (int t = 0; t < 12; ++t) xw[t] = 0.f;
    #pragma unroll
    for (int cq = 0; cq < 16; ++cq) {
        float g0 = gw[(cq * 4 + 0) * 64 + c];
        float g1 = gw[(cq * 4 + 1) * 64 + c];
        float g2 = gw[(cq * 4 + 2) * 64 + c];
        float g3 = gw[(cq * 4 + 3) * 64 + c];
        #pragma unroll
        for (int t = 0; t < 12; ++t) {
            float4 hv = *(const float4*)&tile[nn][t * 64 + cq * 4];
            xw[t] = fmaf(hv.x, g0, xw[t]);
            xw[t] = fmaf(hv.y, g1, xw[t]);
            xw[t] = fmaf(hv.z, g2, xw[t]);
            xw[t] = fmaf(hv.w, g3, xw[t]);
        }
    }
    float* dst = xw_out + (size_t)n * 768 + c;
    #pragma unroll
    for (int t = 0; t < 12; ++t) dst[t * 64] = xw[t];
}

// ---------------- layer B: ELL aggregation (+ fused mean_t + 64x32 head if FINAL) ------
// One wave per dst node; lane L owns row elements {j*256 + 4L + m}, j=0..2, m=0..3
// (flat index i = t*64+c). Whole 3KB source rows gathered with coalesced float4 loads.
#define ACC12(NRM, V0, V1, V2)                                            \
    a[0] = fmaf(NRM, V0.x, a[0]);  a[1] = fmaf(NRM, V0.y, a[1]);          \
    a[2] = fmaf(NRM, V0.z, a[2]);  a[3] = fmaf(NRM, V0.w, a[3]);          \
    a[4] = fmaf(NRM, V1.x, a[4]);  a[5] = fmaf(NRM, V1.y, a[5]);          \
    a[6] = fmaf(NRM, V1.z, a[6]);  a[7] = fmaf(NRM, V1.w, a[7]);          \
    a[8] = fmaf(NRM, V2.x, a[8]);  a[9] = fmaf(NRM, V2.y, a[9]);          \
    a[10] = fmaf(NRM, V2.z, a[10]); a[11] = fmaf(NRM, V2.w, a[11]);

template<bool FINAL>
__global__ __launch_bounds__(256) void k_layer_b(
    const float* __restrict__ xw, const int2* __restrict__ ell,
    const unsigned* __restrict__ cnt, const float* __restrict__ dis,
    const float* __restrict__ gb, float* __restrict__ aggout,
    const float* __restrict__ ow, const float* __restrict__ ob,
    float* __restrict__ dout, int N)
{
    __shared__ __align__(16) float hbuf[4][64];
    const int tid = threadIdx.x;
    const int nn = tid >> 6, L = tid & 63;
    int n = blockIdx.x * 4 + nn;
    if (n >= N) n = N - 1;
    const float dn = dis[n];
    const float d2 = dn * dn;

    float a[12];
    {   // self loop: d2 * xw[n] + gb
        const float* self = xw + (size_t)n * 768 + L * 4;
        float4 v0 = *(const float4*)self;
        float4 v1 = *(const float4*)(self + 256);
        float4 v2 = *(const float4*)(self + 512);
        const int c0 = (L * 4) & 63;
        const float g0 = gb[c0], g1 = gb[c0 + 1], g2 = gb[c0 + 2], g3 = gb[c0 + 3];
        a[0] = fmaf(d2, v0.x, g0); a[1] = fmaf(d2, v0.y, g1);
        a[2] = fmaf(d2, v0.z, g2); a[3] = fmaf(d2, v0.w, g3);
        a[4] = fmaf(d2, v1.x, g0); a[5] = fmaf(d2, v1.y, g1);
        a[6] = fmaf(d2, v1.z, g2); a[7] = fmaf(d2, v1.w, g3);
        a[8] = fmaf(d2, v2.x, g0); a[9] = fmaf(d2, v2.y, g1);
        a[10] = fmaf(d2, v2.z, g2); a[11] = fmaf(d2, v2.w, g3);
    }

    unsigned dg = cnt[n];
    if (dg > MAXDEG) dg = MAXDEG;
    const int2* row = ell + (size_t)n * MAXDEG;
    unsigned e = 0;
    for (; e + 2 <= dg; e += 2) {
        int2 pa = row[e], pb = row[e + 1];
        unsigned sa = (unsigned)pa.x, sb = (unsigned)pb.x;
        if (sa >= (unsigned)N || sb >= (unsigned)N) break;   // defensive
        float na = dis[sa] * __int_as_float(pa.y) * dn;
        float nb = dis[sb] * __int_as_float(pb.y) * dn;
        const float* qa = xw + (size_t)sa * 768 + L * 4;
        const float* qb = xw + (size_t)sb * 768 + L * 4;
        float4 va0 = *(const float4*)qa;
        float4 va1 = *(const float4*)(qa + 256);
        float4 va2 = *(const float4*)(qa + 512);
        float4 vb0 = *(const float4*)qb;
        float4 vb1 = *(const float4*)(qb + 256);
        float4 vb2 = *(const float4*)(qb + 512);
        ACC12(na, va0, va1, va2)
        ACC12(nb, vb0, vb1, vb2)
    }
    for (; e < dg; ++e) {
        int2 pa = row[e];
        unsigned sa = (unsigned)pa.x;
        if (sa >= (unsigned)N) continue;
        float na = dis[sa] * __int_as_float(pa.y) * dn;
        const float* qa = xw + (size_t)sa * 768 + L * 4;
        float4 va0 = *(const float4*)qa;
        float4 va1 = *(const float4*)(qa + 256);
        float4 va2 = *(const float4*)(qa + 512);
        ACC12(na, va0, va1, va2)
    }

    if (!FINAL) {
        float* o = aggout + (size_t)n * 768 + L * 4;
        *(float4*)o = make_float4(a[0], a[1], a[2], a[3]);
        *(float4*)(o + 256) = make_float4(a[4], a[5], a[6], a[7]);
        *(float4*)(o + 512) = make_float4(a[8], a[9], a[10], a[11]);
    } else {
        // mean over T: lane L=16a+b, comp m holds channel 4b+m at t in {a,4+a,8+a};
        // xor over L bits 4,5 sums a=0..3 -> all 12 t's.
        float s0 = a[0] + a[4] + a[8];
        float s1 = a[1] + a[5] + a[9];
        float s2 = a[2] + a[6] + a[10];
        float s3 = a[3] + a[7] + a[11];
        s0 += __shfl_xor(s0, 16); s1 += __shfl_xor(s1, 16);
        s2 += __shfl_xor(s2, 16); s3 += __shfl_xor(s3, 16);
        s0 += __shfl_xor(s0, 32); s1 += __shfl_xor(s1, 32);
        s2 += __shfl_xor(s2, 32); s3 += __shfl_xor(s3, 32);
        if (L < 16) {
            const float inv12 = 1.f / 12.f;
            hbuf[nn][L * 4 + 0] = s0 * inv12;
            hbuf[nn][L * 4 + 1] = s1 * inv12;
            hbuf[nn][L * 4 + 2] = s2 * inv12;
            hbuf[nn][L * 4 + 3] = s3 * inv12;
        }
        __syncthreads();
        if (L < 32) {
            float oa = ob[L];
            #pragma unroll
            for (int cc = 0; cc < 64; ++cc)
                oa = fmaf(hbuf[nn][cc], ow[cc * 32 + L], oa);
            dout[(size_t)n * 32 + L] = oa;
        }
    }
}

extern "C" void kernel_launch(void* const* d_in, const int* in_sizes, int n_in,
                              void* d_out, int out_size, void* d_ws, size_t ws_size,
                              hipStream_t stream)
{
    const float* x   = (const float*)d_in[0];
    const int*   ei  = (const int*)d_in[1];
    const float* ew  = (const float*)d_in[2];
    const float* cw1 = (const float*)d_in[3];
    const float* cb1 = (const float*)d_in[4];
    const float* gm1 = (const float*)d_in[5];
    const float* bt1 = (const float*)d_in[6];
    const float* gw1 = (const float*)d_in[7];
    const float* gb1 = (const float*)d_in[8];
    const float* cw2 = (const float*)d_in[9];
    const float* cb2 = (const float*)d_in[10];
    const float* gm2 = (const float*)d_in[11];
    const float* bt2 = (const float*)d_in[12];
    const float* gw2 = (const float*)d_in[13];
    const float* gb2 = (const float*)d_in[14];
    const float* ow  = (const float*)d_in[15];
    const float* ob  = (const float*)d_in[16];

    const int N = in_sizes[0] / (12 * 32);
    const int E = in_sizes[2];

    // workspace layout
    char* p0 = (char*)d_ws;
    char* p = p0;
    float* deg = (float*)p;          p += (size_t)N * 4;
    unsigned* cnt = (unsigned*)p;    p += (size_t)N * 4;   // adjacent to deg: one memset
    float* dis = (float*)p;          p += (size_t)N * 4;
    p = (char*)(((uintptr_t)p + 255) & ~(uintptr_t)255);
    int2* ell = (int2*)p;            p += (size_t)N * MAXDEG * 8;
    p = (char*)(((uintptr_t)p + 255) & ~(uintptr_t)255);
    float* bufA = (float*)p;         p += (size_t)N * 768 * 4;
    float* bufB = (float*)p;         p += (size_t)N * 768 * 4;

    const size_t need = (size_t)(p - p0);
    if (ws_size < need) {
        hipMemsetAsync(d_out, 0, (size_t)out_size * 4, stream);   // sentinel
        return;
    }

    hipMemsetAsync(deg, 0, (size_t)N * 8, stream);

    const int eb  = (E + 255) / 256;
    const int nb4 = (N + 3) / 4;
    k_build_ell<<<eb, 256, 0, stream>>>(ei, ew, deg, cnt, ell, E);
    k_dis<<<(N + 255) / 256, 256, 0, stream>>>(deg, dis, N);

    // layer 1: conv+IN+ReLU+GEMM fused -> bufA ([N][768]); agg -> bufB
    k_layer_a<32, true ><<<nb4, 256, 0, stream>>>(x, cw1, cb1, gm1, bt1, gw1, bufA, N);
    k_layer_b<false><<<nb4, 256, 0, stream>>>(bufA, ell, cnt, dis, gb1, bufB, nullptr, nullptr, nullptr, N);
    // layer 2 + fused mean/head
    k_layer_a<64, false><<<nb4, 256, 0, stream>>>(bufB, cw2, cb2, gm2, bt2, gw2, bufA, N);
    k_layer_b<true ><<<nb4, 256, 0, stream>>>(bufA, ell, cnt, dis, gb2, nullptr, ow, ob, (float*)d_out, N);
}

// Round 7
// 384.455 us; speedup vs baseline: 2.6146x; 1.1592x over previous
//
#include <hip/hip_runtime.h>
#include <hip/hip_bf16.h>
#include <stdint.h>

#define MAXDEG 64

static __device__ __forceinline__ float us2f(unsigned short u) {
    union { float f; unsigned int i; } cv; cv.i = ((unsigned int)u) << 16; return cv.f;
}
static __device__ __forceinline__ unsigned short f2us(float f) {
    __hip_bfloat16 h = __float2bfloat16(f);   // RNE
    return *(unsigned short*)&h;
}

// ---------------- setup: degree + ELL adjacency (incoming edges per dst) ----------------
__global__ void k_build_ell(const int* __restrict__ ei, const float* __restrict__ ew,
                            float* __restrict__ deg, unsigned* __restrict__ cnt,
                            int2* __restrict__ ell, int E)
{
    int e = blockIdx.x * 256 + threadIdx.x;
    if (e >= E) return;
    int s = ei[e], d = ei[E + e];
    float w = ew[e];
    atomicAdd(&deg[d], w);
    unsigned slot = atomicAdd(&cnt[d], 1u);
    if (slot < MAXDEG) ell[(size_t)d * MAXDEG + slot] = make_int2(s, __float_as_int(w));
}

__global__ void k_dis(const float* __restrict__ deg, float* __restrict__ dis, int N)
{
    int i = blockIdx.x * 256 + threadIdx.x;
    if (i < N) dis[i] = rsqrtf(deg[i] + 1.0f);
}

// ---------------- layer A: conv1d(K=3,pad1) + InstanceNorm(T) + ReLU + (h @ gw) --------
// One wave per node (lane = out channel), 4 nodes per block.
// Conv weights staged in LDS as bf16 (x and accumulation stay f32; gw stays f32).
// LDS: CIN=64: 24.8K weights + 14.3K tile = 39.2K -> 4 blocks/CU; VGPR forced <=128.
template<int CIN, bool FIRST>
__global__ __launch_bounds__(256, 4) void k_layer_a(
    const float* __restrict__ x_in,
    const float* __restrict__ cw,     // [64][CIN][3] f32
    const float* __restrict__ cb, const float* __restrict__ gm, const float* __restrict__ bt,
    const float* __restrict__ gw,     // [64][64] f32 (global, L2-broadcast)
    float* __restrict__ xw_out, int N)
{
    constexpr int WROWS = CIN * 3;
    constexpr int WSTR  = WROWS + 2;             // even (ushort2-aligned); 194/98 -> 2-way bank alias only
    constexpr int TILE  = (14 * CIN > 768) ? 14 * CIN : 768;
    __shared__ unsigned short lwh[64 * WSTR];    // [c][ci*3+k] bf16
    __shared__ __align__(16) float tile[4][TILE];

    const int tid = threadIdx.x;
    const int nn = tid >> 6;
    const int c = tid & 63;
    int n = blockIdx.x * 4 + nn;
    if (n >= N) n = N - 1;

    // cooperative weight staging f32 -> bf16
    for (int g = tid; g < 64 * WROWS; g += 256) {
        int row = g / WROWS, col = g - row * WROWS;
        lwh[row * WSTR + col] = f2us(cw[g]);
    }

    // stage x into tile rows t=-1..12 (rows 0..13), row stride CIN (wave-private slice)
    if (FIRST) {
        #pragma unroll
        for (int it = 0; it < (12 * CIN) / 64; ++it) {
            int i = it * 64 + c;
            int t = i / CIN, ci = i - t * CIN;
            tile[nn][(t + 1) * CIN + ci] = x_in[((size_t)t * N + n) * CIN + ci];
        }
    } else {
        const float* src = x_in + (size_t)n * 768;
        #pragma unroll
        for (int j = 0; j < 3; ++j)
            *(float4*)&tile[nn][CIN + j * 256 + c * 4] = *(const float4*)(src + j * 256 + c * 4);
    }
    if (c < CIN) { tile[nn][c] = 0.f; tile[nn][13 * CIN + c] = 0.f; }
    __syncthreads();   // weights staged by all threads

    // conv: acc[t] = bias + sum_ci sum_k x[t+k-1][ci] * w[c][ci][k]
    float acc[12];
    {
        const float bias = cb[c];
        #pragma unroll
        for (int t = 0; t < 12; ++t) acc[t] = bias;
        const float* xt = tile[nn];
        const unsigned short* wrow = lwh + c * WSTR;
        #pragma unroll
        for (int cq = 0; cq < CIN / 4; ++cq) {
            float wv[12];
            #pragma unroll
            for (int rp = 0; rp < 6; ++rp) {
                ushort2 pw = *(const ushort2*)(wrow + cq * 12 + rp * 2);
                wv[rp * 2 + 0] = us2f(pw.x);
                wv[rp * 2 + 1] = us2f(pw.y);
            }
            float4 r0 = *(const float4*)(xt + cq * 4);
            float4 r1 = *(const float4*)(xt + CIN + cq * 4);
            #pragma unroll
            for (int t = 0; t < 12; ++t) {
                float4 r2 = *(const float4*)(xt + (t + 2) * CIN + cq * 4);
                acc[t] = fmaf(r0.x, wv[0], acc[t]);
                acc[t] = fmaf(r1.x, wv[1], acc[t]);
                acc[t] = fmaf(r2.x, wv[2], acc[t]);
                acc[t] = fmaf(r0.y, wv[3], acc[t]);
                acc[t] = fmaf(r1.y, wv[4], acc[t]);
                acc[t] = fmaf(r2.y, wv[5], acc[t]);
                acc[t] = fmaf(r0.z, wv[6], acc[t]);
                acc[t] = fmaf(r1.z, wv[7], acc[t]);
                acc[t] = fmaf(r2.z, wv[8], acc[t]);
                acc[t] = fmaf(r0.w, wv[9], acc[t]);
                acc[t] = fmaf(r1.w, wv[10], acc[t]);
                acc[t] = fmaf(r2.w, wv[11], acc[t]);
                r0 = r1; r1 = r2;
            }
        }
    }
    // InstanceNorm over T (biased var) + affine + ReLU  (register-only per (n,c))
    float mu = 0.f;
    #pragma unroll
    for (int t = 0; t < 12; ++t) mu += acc[t];
    mu *= (1.f / 12.f);
    float var = 0.f;
    #pragma unroll
    for (int t = 0; t < 12; ++t) { float d = acc[t] - mu; var = fmaf(d, d, var); }
    var *= (1.f / 12.f);
    const float sc = rsqrtf(var + 1e-5f) * gm[c];
    const float sb = bt[c];
    // reuse wave-private tile slice as h[t][64] (no cross-wave access -> no barrier)
    #pragma unroll
    for (int t = 0; t < 12; ++t) {
        float h = fmaf(acc[t] - mu, sc, sb);
        tile[nn][t * 64 + c] = h > 0.f ? h : 0.f;
    }

    // xw[t][d] = sum_cc h[t][cc] * gw[cc][d]; d = lane; gw rows from global (coalesced, f32 exact)
    float xw[12];
    #pragma unroll
    for (int t = 0; t < 12; ++t) xw[t] = 0.f;
    #pragma unroll
    for (int cq = 0; cq < 16; ++cq) {
        float g0 = gw[(cq * 4 + 0) * 64 + c];
        float g1 = gw[(cq * 4 + 1) * 64 + c];
        float g2 = gw[(cq * 4 + 2) * 64 + c];
        float g3 = gw[(cq * 4 + 3) * 64 + c];
        #pragma unroll
        for (int t = 0; t < 12; ++t) {
            float4 hv = *(const float4*)&tile[nn][t * 64 + cq * 4];
            xw[t] = fmaf(hv.x, g0, xw[t]);
            xw[t] = fmaf(hv.y, g1, xw[t]);
            xw[t] = fmaf(hv.z, g2, xw[t]);
            xw[t] = fmaf(hv.w, g3, xw[t]);
        }
    }
    float* dst = xw_out + (size_t)n * 768 + c;
    #pragma unroll
    for (int t = 0; t < 12; ++t) dst[t * 64] = xw[t];
}

// ---------------- layer B: ELL aggregation (+ fused mean_t + 64x32 head if FINAL) ------
// One wave per dst node; lane L owns row elements {j*256 + 4L + m}, j=0..2, m=0..3
// (flat index i = t*64+c). Whole 3KB source rows gathered with coalesced float4 loads.
#define ACC12(NRM, V0, V1, V2)                                            \
    a[0] = fmaf(NRM, V0.x, a[0]);  a[1] = fmaf(NRM, V0.y, a[1]);          \
    a[2] = fmaf(NRM, V0.z, a[2]);  a[3] = fmaf(NRM, V0.w, a[3]);          \
    a[4] = fmaf(NRM, V1.x, a[4]);  a[5] = fmaf(NRM, V1.y, a[5]);          \
    a[6] = fmaf(NRM, V1.z, a[6]);  a[7] = fmaf(NRM, V1.w, a[7]);          \
    a[8] = fmaf(NRM, V2.x, a[8]);  a[9] = fmaf(NRM, V2.y, a[9]);          \
    a[10] = fmaf(NRM, V2.z, a[10]); a[11] = fmaf(NRM, V2.w, a[11]);

template<bool FINAL>
__global__ __launch_bounds__(256) void k_layer_b(
    const float* __restrict__ xw, const int2* __restrict__ ell,
    const unsigned* __restrict__ cnt, const float* __restrict__ dis,
    const float* __restrict__ gb, float* __restrict__ aggout,
    const float* __restrict__ ow, const float* __restrict__ ob,
    float* __restrict__ dout, int N)
{
    __shared__ __align__(16) float hbuf[4][64];
    const int tid = threadIdx.x;
    const int nn = tid >> 6, L = tid & 63;
    int n = blockIdx.x * 4 + nn;
    if (n >= N) n = N - 1;
    const float dn = dis[n];
    const float d2 = dn * dn;

    float a[12];
    {   // self loop: d2 * xw[n] + gb
        const float* self = xw + (size_t)n * 768 + L * 4;
        float4 v0 = *(const float4*)self;
        float4 v1 = *(const float4*)(self + 256);
        float4 v2 = *(const float4*)(self + 512);
        const int c0 = (L * 4) & 63;
        const float g0 = gb[c0], g1 = gb[c0 + 1], g2 = gb[c0 + 2], g3 = gb[c0 + 3];
        a[0] = fmaf(d2, v0.x, g0); a[1] = fmaf(d2, v0.y, g1);
        a[2] = fmaf(d2, v0.z, g2); a[3] = fmaf(d2, v0.w, g3);
        a[4] = fmaf(d2, v1.x, g0); a[5] = fmaf(d2, v1.y, g1);
        a[6] = fmaf(d2, v1.z, g2); a[7] = fmaf(d2, v1.w, g3);
        a[8] = fmaf(d2, v2.x, g0); a[9] = fmaf(d2, v2.y, g1);
        a[10] = fmaf(d2, v2.z, g2); a[11] = fmaf(d2, v2.w, g3);
    }

    unsigned dg = cnt[n];
    if (dg > MAXDEG) dg = MAXDEG;
    const int2* row = ell + (size_t)n * MAXDEG;
    unsigned e = 0;
    for (; e + 2 <= dg; e += 2) {
        int2 pa = row[e], pb = row[e + 1];
        unsigned sa = (unsigned)pa.x, sb = (unsigned)pb.x;
        if (sa >= (unsigned)N || sb >= (unsigned)N) break;   // defensive
        float na = dis[sa] * __int_as_float(pa.y) * dn;
        float nb = dis[sb] * __int_as_float(pb.y) * dn;
        const float* qa = xw + (size_t)sa * 768 + L * 4;
        const float* qb = xw + (size_t)sb * 768 + L * 4;
        float4 va0 = *(const float4*)qa;
        float4 va1 = *(const float4*)(qa + 256);
        float4 va2 = *(const float4*)(qa + 512);
        float4 vb0 = *(const float4*)qb;
        float4 vb1 = *(const float4*)(qb + 256);
        float4 vb2 = *(const float4*)(qb + 512);
        ACC12(na, va0, va1, va2)
        ACC12(nb, vb0, vb1, vb2)
    }
    for (; e < dg; ++e) {
        int2 pa = row[e];
        unsigned sa = (unsigned)pa.x;
        if (sa >= (unsigned)N) continue;
        float na = dis[sa] * __int_as_float(pa.y) * dn;
        const float* qa = xw + (size_t)sa * 768 + L * 4;
        float4 va0 = *(const float4*)qa;
        float4 va1 = *(const float4*)(qa + 256);
        float4 va2 = *(const float4*)(qa + 512);
        ACC12(na, va0, va1, va2)
    }

    if (!FINAL) {
        float* o = aggout + (size_t)n * 768 + L * 4;
        *(float4*)o = make_float4(a[0], a[1], a[2], a[3]);
        *(float4*)(o + 256) = make_float4(a[4], a[5], a[6], a[7]);
        *(float4*)(o + 512) = make_float4(a[8], a[9], a[10], a[11]);
    } else {
        // mean over T: lane L=16a+b, comp m holds channel 4b+m at t in {a,4+a,8+a};
        // xor over L bits 4,5 sums a=0..3 -> all 12 t's.
        float s0 = a[0] + a[4] + a[8];
        float s1 = a[1] + a[5] + a[9];
        float s2 = a[2] + a[6] + a[10];
        float s3 = a[3] + a[7] + a[11];
        s0 += __shfl_xor(s0, 16); s1 += __shfl_xor(s1, 16);
        s2 += __shfl_xor(s2, 16); s3 += __shfl_xor(s3, 16);
        s0 += __shfl_xor(s0, 32); s1 += __shfl_xor(s1, 32);
        s2 += __shfl_xor(s2, 32); s3 += __shfl_xor(s3, 32);
        if (L < 16) {
            const float inv12 = 1.f / 12.f;
            hbuf[nn][L * 4 + 0] = s0 * inv12;
            hbuf[nn][L * 4 + 1] = s1 * inv12;
            hbuf[nn][L * 4 + 2] = s2 * inv12;
            hbuf[nn][L * 4 + 3] = s3 * inv12;
        }
        __syncthreads();
        if (L < 32) {
            float oa = ob[L];
            #pragma unroll
            for (int cc = 0; cc < 64; ++cc)
                oa = fmaf(hbuf[nn][cc], ow[cc * 32 + L], oa);
            dout[(size_t)n * 32 + L] = oa;
        }
    }
}

extern "C" void kernel_launch(void* const* d_in, const int* in_sizes, int n_in,
                              void* d_out, int out_size, void* d_ws, size_t ws_size,
                              hipStream_t stream)
{
    const float* x   = (const float*)d_in[0];
    const int*   ei  = (const int*)d_in[1];
    const float* ew  = (const float*)d_in[2];
    const float* cw1 = (const float*)d_in[3];
    const float* cb1 = (const float*)d_in[4];
    const float* gm1 = (const float*)d_in[5];
    const float* bt1 = (const float*)d_in[6];
    const float* gw1 = (const float*)d_in[7];
    const float* gb1 = (const float*)d_in[8];
    const float* cw2 = (const float*)d_in[9];
    const float* cb2 = (const float*)d_in[10];
    const float* gm2 = (const float*)d_in[11];
    const float* bt2 = (const float*)d_in[12];
    const float* gw2 = (const float*)d_in[13];
    const float* gb2 = (const float*)d_in[14];
    const float* ow  = (const float*)d_in[15];
    const float* ob  = (const float*)d_in[16];

    const int N = in_sizes[0] / (12 * 32);
    const int E = in_sizes[2];

    // workspace layout
    char* p0 = (char*)d_ws;
    char* p = p0;
    float* deg = (float*)p;          p += (size_t)N * 4;
    unsigned* cnt = (unsigned*)p;    p += (size_t)N * 4;   // adjacent to deg: one memset
    float* dis = (float*)p;          p += (size_t)N * 4;
    p = (char*)(((uintptr_t)p + 255) & ~(uintptr_t)255);
    int2* ell = (int2*)p;            p += (size_t)N * MAXDEG * 8;
    p = (char*)(((uintptr_t)p + 255) & ~(uintptr_t)255);
    float* bufA = (float*)p;         p += (size_t)N * 768 * 4;
    float* bufB = (float*)p;         p += (size_t)N * 768 * 4;

    const size_t need = (size_t)(p - p0);
    if (ws_size < need) {
        hipMemsetAsync(d_out, 0, (size_t)out_size * 4, stream);   // sentinel
        return;
    }

    hipMemsetAsync(deg, 0, (size_t)N * 8, stream);

    const int eb  = (E + 255) / 256;
    const int nb4 = (N + 3) / 4;
    k_build_ell<<<eb, 256, 0, stream>>>(ei, ew, deg, cnt, ell, E);
    k_dis<<<(N + 255) / 256, 256, 0, stream>>>(deg, dis, N);

    // layer 1: conv+IN+ReLU+GEMM fused -> bufA ([N][768]); agg -> bufB
    k_layer_a<32, true ><<<nb4, 256, 0, stream>>>(x, cw1, cb1, gm1, bt1, gw1, bufA, N);
    k_layer_b<false><<<nb4, 256, 0, stream>>>(bufA, ell, cnt, dis, gb1, bufB, nullptr, nullptr, nullptr, N);
    // layer 2 + fused mean/head
    k_layer_a<64, false><<<nb4, 256, 0, stream>>>(bufB, cw2, cb2, gm2, bt2, gw2, bufA, N);
    k_layer_b<true ><<<nb4, 256, 0, stream>>>(bufA, ell, cnt, dis, gb2, nullptr, ow, ob, (float*)d_out, N);
}